// Round 8
// baseline (2099.979 us; speedup 1.0000x reference)
//
#include <hip/hip_runtime.h>
#include <cstdint>
#include <cstddef>

typedef __attribute__((ext_vector_type(8))) short short8;   // 8 bf16 (4 VGPRs)
typedef __attribute__((ext_vector_type(4))) short bfx4;     // 4 bf16 (8 B)
typedef __attribute__((ext_vector_type(4))) float f32x4;

#define HH     100
#define G4     400
#define NCOL   416          // 400 gates + 5 logits + 11 pad = 26 tiles of 16
#define NTIL   26
#define KTN    3            // 3 k-tiles of 32 -> k<96 via MFMA
#define KRES   96           // k=96..99 residual in f32
#define BTOT   8192
#define TST    512
#define GR     16           // rows per block
#define NBLK   512          // 2 blocks/CU -> independent barrier domains
#define BLOCK  256          // 4 waves x 64; 2 blocks/CU = 2 waves/SIMD -> 256 regs
#define ZW     420          // z_lds row stride (words)
#define TANHC  1.5f
#define EPSF   1e-9f

__device__ unsigned short d_Bhi[NTIL*KTN*64*8];  // [W_h|W_ops|0] hi, B-frag order
__device__ unsigned short d_Blo[NTIL*KTN*64*8];  // lo residual
__device__ float d_Ep2[6*G4];                    // emb @ W_x   [e][cell][gate]
__device__ float d_WresG[NCOL*4];                // rows 96..99 of [W_h|W_ops|0], [n][q]
__device__ float d_Z0[(size_t)BTOT*G4];          // x0 @ W_x    [b][n]

static __device__ __forceinline__ unsigned short bf16hi(float f){
  unsigned u = __float_as_uint(f);
  return (unsigned short)((u + 0x7FFFu + ((u>>16)&1u)) >> 16);   // RNE
}
static __device__ __forceinline__ float bf16f(unsigned short s){
  return __uint_as_float(((unsigned)s)<<16);
}
static __device__ __forceinline__ float frcp(float x){ return __builtin_amdgcn_rcpf(x); }
static __device__ __forceinline__ float sigf(float x){ return frcp(1.0f + __expf(-x)); }
static __device__ __forceinline__ float tanh_f(float x){ return 1.0f - 2.0f*frcp(__expf(2.0f*x) + 1.0f); }

// ---- setup kernels (round-0 verbatim) ------------------------------------

// B-frag order for 16x16x32: n = tile*16 + (lane&15), k = kt*32 + (lane>>4)*8 + i
__global__ void setup_bpack(const float* __restrict__ Wh, const float* __restrict__ Wops){
  int idx = blockIdx.x*blockDim.x + threadIdx.x;     // NTIL*KTN*64 = 4992
  if (idx >= NTIL*KTN*64) return;
  int tile = idx/(KTN*64), rem = idx - tile*(KTN*64), kt = rem>>6, ln = rem&63;
  int n = tile*16 + (ln & 15);
  #pragma unroll
  for (int i = 0; i < 8; ++i){
    int k = kt*32 + (ln>>4)*8 + i;                   // k < 96 always
    float w = 0.f;
    if (n < G4)          w = Wh[k*G4 + n];
    else if (n < G4+5)   w = Wops[k*5 + (n - G4)];
    unsigned short hi = bf16hi(w);
    unsigned short lo = bf16hi(w - bf16f(hi));
    d_Bhi[idx*8+i] = hi;
    d_Blo[idx*8+i] = lo;
  }
}

__global__ void setup_misc(const float* __restrict__ emb, const float* __restrict__ Wx,
                           const float* __restrict__ Wh, const float* __restrict__ Wops){
  int idx = blockIdx.x*blockDim.x + threadIdx.x;
  if (idx < 6*G4){                                   // Ep2 [e][cell][gate]
    int e = idx/G4, r2 = idx - e*G4, je = r2>>2, g = r2&3;
    float s = 0.f;
    for (int k = 0; k < HH; ++k) s = fmaf(emb[e*HH+k], Wx[k*G4 + g*HH + je], s);
    d_Ep2[idx] = s;
  } else if (idx < 6*G4 + NCOL*4){                   // residual rows 96..99
    int i = idx - 6*G4, n = i>>2, q = i&3;
    float w = 0.f;
    if (n < G4)        w = Wh[(KRES+q)*G4 + n];
    else if (n < G4+5) w = Wops[(KRES+q)*5 + (n - G4)];
    d_WresG[i] = w;
  }
}

// Z0 = x0 @ W_x, stored [b][n]
__global__ __launch_bounds__(256) void setup_z0(const float* __restrict__ x0,
                                                const float* __restrict__ Wx){
  __shared__ float xs[64*101];
  const int bb = blockIdx.x * 64;                    // 128 blocks
  for (int i = threadIdx.x; i < 64*HH; i += 256){
    int r = i/HH, k = i - r*HH;
    xs[r*101 + k] = x0[(size_t)(bb + r)*HH + k];
  }
  __syncthreads();
  const int bl = threadIdx.x & 63;
  for (int ng = threadIdx.x >> 6; ng < HH; ng += 4){
    f32x4 a = {0.f,0.f,0.f,0.f};
    for (int k = 0; k < HH; ++k){
      f32x4 w = *(const f32x4*)&Wx[k*G4 + ng*4];
      a += w * xs[bl*101 + k];
    }
    *(f32x4*)&d_Z0[(size_t)(bb + bl)*G4 + ng*4] = a;
  }
}

// ---- main persistent kernel ---------------------------------------------
// 512 blocks x 16 rows, 4 waves x 64 = 256 threads, 2 blocks/CU co-resident
// (8 waves/CU = 2 waves/SIMD -> 256-reg budget; LDS ~50KB x2 fits 160KB).
// Each block has a PRIVATE barrier: block A's drain fills with block B's work
// (r1 failed this at 13-wave blocks: 7 waves/SIMD -> 73-reg budget; 4-wave
// blocks give 256). Inner math = r7 verbatim: 3-term bf16x2 MFMA, register
// sampler via swapped tile 25 (r7's mt=0 path), r0/r4 E formulas.
// Tiles: w0 {0-5,24}=7  w1 {6-11}=6  w2 {12-17,23}=7  w3 {18-22}=5 + 25 swapped.
// E: pass1 all 256 thr (jg=tid>>4); pass2 tid 64..207 (jg=24-((tid-64)>>4),
// h_res on w1 lanes 0-15); gumbel tid 208..223.

__global__ __launch_bounds__(BLOCK, 2) void rnn_main(
    const float* __restrict__ u, float* __restrict__ out)
{
  __shared__ __align__(16) float z_lds[GR*ZW];                  // 26880 B
  __shared__ __align__(16) unsigned short fhi[KTN*64*8];        //  3072 B
  __shared__ __align__(16) unsigned short flo[KTN*64*8];        //  3072 B
  __shared__ __align__(16) float h_res[4*GR];                   //   256 B [q][r]
  __shared__ __align__(16) float Ep2_l[6*G4];                   //  9600 B
  __shared__ __align__(16) float Wres_l[NCOL*4];                //  6656 B
  __shared__ __align__(16) float gn_lds[GR*5];                  //   320 B
  __shared__ int op_lds[GR];                                    //    64 B

  const int tid  = threadIdx.x;
  const int wave = tid >> 6;
  const int lane = tid & 63;
  const int cn   = lane & 15;       // col-in-tile (B,C) / row-in-tile (A)
  const int q4   = lane >> 4;       // quad
  const int row0 = blockIdx.x * GR;
  const int rE   = tid & 15;        // E row

  // anti-phase the co-resident pair (i, i+256 under XCD round-robin):
  // offset barriers ~3000 cy so A's drains overlap B's compute.
  if (blockIdx.x & 256){
    __builtin_amdgcn_s_sleep(24);
    __builtin_amdgcn_s_sleep(24);
  }

  for (int i = tid; i < 6*G4;   i += BLOCK) Ep2_l[i]  = d_Ep2[i];
  for (int i = tid; i < NCOL*4; i += BLOCK) Wres_l[i] = d_WresG[i];

  // persistent B-fragments, 5-7 tiles per wave (tile ids per header comment)
  const int ntl = (wave==0 || wave==2) ? 7 : 6;      // tiles LOADED
  const int ngt = (wave==3) ? 5 : ntl;               // tiles computed normally
  int tids[7];
  #pragma unroll
  for (int tl = 0; tl < 7; ++tl)
    tids[tl] = (wave==0) ? (tl<6 ? tl      : 24)
             : (wave==1) ? (6+tl)
             : (wave==2) ? (tl<6 ? 12+tl   : 23)
             :             (tl<5 ? 18+tl   : 25);    // w3 slot 5 = logits tile
  short8 bh[7][KTN], bl[7][KTN];
  {
    const short8* bph = (const short8*)d_Bhi;
    const short8* bpl = (const short8*)d_Blo;
    #pragma unroll
    for (int tl = 0; tl < 7; ++tl) if (tl < ntl)
      #pragma unroll
      for (int kt = 0; kt < KTN; ++kt){
        int fi = (tids[tl]*KTN + kt)*64 + lane;
        bh[tl][kt] = bph[fi];
        bl[tl][kt] = bpl[fi];
      }
  }

  float cs1[4] = {0.f,0.f,0.f,0.f};   // pass-1 cells (jg = tid>>4)
  float cs2[4] = {0.f,0.f,0.f,0.f};   // pass-2 cells (jg = 24-((tid-64)>>4))
  float lp_acc = 0.f, ent_acc = 0.f;

  for (int t = 0; t <= TST; ++t){
    // gumbel u prefetch (tid 208..223); HBM latency hides under G+E
    float upr[5];
    if (t < TST && tid >= 208 && tid < 224){
      const float* up = u + ((size_t)t*BTOT + row0 + (tid - 208))*5;
      #pragma unroll
      for (int o = 0; o < 5; ++o) upr[o] = up[o];
    }

    if (t == 0){
      // stage z_0 = x0 @ W_x (gates only)
      for (int i = tid; i < GR*HH; i += BLOCK){
        int r = i/HH, c4 = i - r*HH;
        *(f32x4*)&z_lds[r*ZW + c4*4] =
          *(const f32x4*)&d_Z0[(size_t)(row0 + r)*G4 + c4*4];
      }
    } else {
      // ---- G: z_t = h_t @ [W_h|W_ops]  (3-term MFMA k<96 + f32 residual) ----
      short8 ah[KTN], al[KTN];
      #pragma unroll
      for (int kt = 0; kt < KTN; ++kt){
        ah[kt] = *(const short8*)&fhi[(kt*64 + lane)*8];
        al[kt] = *(const short8*)&flo[(kt*64 + lane)*8];
      }
      f32x4 hq[4];
      #pragma unroll
      for (int q = 0; q < 4; ++q)                       // broadcast reads [q][r]
        hq[q] = *(const f32x4*)&h_res[q*GR + q4*4];
      #pragma unroll
      for (int tl = 0; tl < 7; ++tl) if (tl < ngt){
        const int n = tids[tl]*16 + cn;
        f32x4 acc = {0.f,0.f,0.f,0.f};
        #pragma unroll
        for (int kt = 0; kt < KTN; ++kt){
          acc = __builtin_amdgcn_mfma_f32_16x16x32_bf16(ah[kt], bh[tl][kt], acc, 0,0,0);
          acc = __builtin_amdgcn_mfma_f32_16x16x32_bf16(al[kt], bh[tl][kt], acc, 0,0,0);
          acc = __builtin_amdgcn_mfma_f32_16x16x32_bf16(ah[kt], bl[tl][kt], acc, 0,0,0);
        }
        f32x4 wr = *(const f32x4*)&Wres_l[n*4];
        #pragma unroll
        for (int q = 0; q < 4; ++q) acc += hq[q] * wr[q];
        const int rowb = q4*4;                          // C: row=q4*4+reg, col=cn
        #pragma unroll
        for (int i = 0; i < 4; ++i)
          z_lds[(rowb + i)*ZW + n] = acc[i];
      }
      // ---- sampling for step t-1 (wave 3; logits in registers, r7 mt=0 path) ----
      if (wave == 3){
        f32x4 accT = {0.f,0.f,0.f,0.f};                 // swapped tile 25
        #pragma unroll
        for (int kt = 0; kt < KTN; ++kt){               // term order = normal path
          accT = __builtin_amdgcn_mfma_f32_16x16x32_bf16(bh[5][kt], ah[kt], accT, 0,0,0);
          accT = __builtin_amdgcn_mfma_f32_16x16x32_bf16(bh[5][kt], al[kt], accT, 0,0,0);
          accT = __builtin_amdgcn_mfma_f32_16x16x32_bf16(bl[5][kt], ah[kt], accT, 0,0,0);
        }
        {                                               // f32 residual for logits
          float h0 = h_res[0*GR + cn], h1 = h_res[1*GR + cn];
          float h2 = h_res[2*GR + cn], h3 = h_res[3*GR + cn];
          #pragma unroll
          for (int i = 0; i < 4; ++i){
            f32x4 wr = *(const f32x4*)&Wres_l[(G4 + q4*4 + i)*4];  // rows >404 are 0
            accT[i] += h0*wr.x + h1*wr.y + h2*wr.z + h3*wr.w;
          }
        }
        float o4lo = __shfl_down(accT[0], 16);          // o=4 lives in lane r+16, reg 0
        if (lane < 16){
          const int r = lane;
          float raw[5] = {accT[0], accT[1], accT[2], accT[3], o4lo};
          float l[5];
          #pragma unroll
          for (int o = 0; o < 5; ++o) l[o] = TANHC * tanh_f(raw[o]);
          int op = 0; float best = -1e30f;
          #pragma unroll
          for (int o = 0; o < 5; ++o){
            float v = l[o] + gn_lds[r*5 + o];
            if (v > best){ best = v; op = o; }          // strict >: first-max ties
          }
          float mx = fmaxf(fmaxf(fmaxf(l[0],l[1]), fmaxf(l[2],l[3])), l[4]);
          float se = 0.f;
          #pragma unroll
          for (int o = 0; o < 5; ++o) se += __expf(l[o] - mx);
          float lse = mx + __logf(se);
          float cur = lse - l[op];
          lp_acc  += cur;
          ent_acc += cur * __expf(-cur);
          op_lds[r] = op;
          out[2*BTOT + (size_t)(t-1)*BTOT + row0 + r] = (float)op;
        }
      }
    }
    if (t == TST) break;
    __syncthreads();   // b1: z_t + op_{t-1} ready

    // ---- E: LSTM elementwise (r7 body), op hoisted above both passes ----
    const int opv = (t > 0) ? op_lds[rE] : 0;
    // pass 1: all 256 threads, jg = tid>>4 in 0..15 (cells 0..63)
    {
      const int jg = tid >> 4;
      f32x4 zg[4];
      #pragma unroll
      for (int g = 0; g < 4; ++g)
        zg[g] = *(const f32x4*)&z_lds[rE*ZW + g*HH + jg*4];
      if (t > 0){
        #pragma unroll
        for (int i = 0; i < 4; ++i){
          f32x4 e4 = *(const f32x4*)&Ep2_l[opv*G4 + (jg*4 + i)*4];
          zg[0][i] += e4.x; zg[1][i] += e4.y; zg[2][i] += e4.z; zg[3][i] += e4.w;
        }
      }
      float hv[4];
      #pragma unroll
      for (int i = 0; i < 4; ++i){
        float cn_ = sigf(zg[1][i])*cs1[i] + sigf(zg[0][i])*tanh_f(zg[2][i]);
        cs1[i] = cn_;
        hv[i] = sigf(zg[3][i])*tanh_f(cn_);
      }
      bfx4 h4, l4;                                       // jg<16 -> always frags
      #pragma unroll
      for (int i = 0; i < 4; ++i){
        unsigned short hi = bf16hi(hv[i]);
        h4[i] = (short)hi;
        l4[i] = (short)bf16hi(hv[i] - bf16f(hi));
      }
      const int kt   = jg >> 3;
      const int lf   = rE | (((jg >> 1) & 3) << 4);
      const int j0   = (jg & 1) * 4;
      const int base = (kt*64 + lf)*8 + j0;
      *(bfx4*)&fhi[base] = h4;
      *(bfx4*)&flo[base] = l4;
    }
    // pass 2: tid 64..207 -> jg 24..16 (jg24/h_res on w1 lanes 0-15);
    // tid 208..223 -> gumbel noise
    if (tid >= 64 && tid < 208){
      const int jg = 24 - ((tid - 64) >> 4);
      const int c0 = jg*4;
      f32x4 zg[4];
      #pragma unroll
      for (int g = 0; g < 4; ++g)
        zg[g] = *(const f32x4*)&z_lds[rE*ZW + g*HH + c0];
      if (t > 0){
        #pragma unroll
        for (int i = 0; i < 4; ++i){
          f32x4 e4 = *(const f32x4*)&Ep2_l[opv*G4 + (c0 + i)*4];
          zg[0][i] += e4.x; zg[1][i] += e4.y; zg[2][i] += e4.z; zg[3][i] += e4.w;
        }
      }
      float hv[4];
      #pragma unroll
      for (int i = 0; i < 4; ++i){
        float cn_ = sigf(zg[1][i])*cs2[i] + sigf(zg[0][i])*tanh_f(zg[2][i]);
        cs2[i] = cn_;
        hv[i] = sigf(zg[3][i])*tanh_f(cn_);
      }
      if (jg < 24){                                      // jg 16..23 -> frags
        bfx4 h4, l4;
        #pragma unroll
        for (int i = 0; i < 4; ++i){
          unsigned short hi = bf16hi(hv[i]);
          h4[i] = (short)hi;
          l4[i] = (short)bf16hi(hv[i] - bf16f(hi));
        }
        const int kt   = jg >> 3;                        // = 2
        const int lf   = rE | (((jg >> 1) & 3) << 4);
        const int j0   = (jg & 1) * 4;
        const int base = (kt*64 + lf)*8 + j0;
        *(bfx4*)&fhi[base] = h4;
        *(bfx4*)&flo[base] = l4;
      } else {                                           // jg==24: k=96..99 residual
        #pragma unroll
        for (int i = 0; i < 4; ++i) h_res[i*GR + rE] = hv[i];
      }
    } else if (tid >= 208 && tid < 224){
      // gumbel noise for u[t] (consumed at G_{t+1}); loads issued at loop top
      int r = tid - 208;
      #pragma unroll
      for (int o = 0; o < 5; ++o)
        gn_lds[r*5 + o] = -__logf(-__logf(upr[o] + EPSF) + EPSF);
    }
    __syncthreads();   // b2: h_{t+1} frags + h_res + gn ready
  }

  if (wave == 3 && lane < 16){
    out[row0 + lane]        = lp_acc;
    out[BTOT + row0 + lane] = ent_acc;
  }
}

extern "C" void kernel_launch(void* const* d_in, const int* in_sizes, int n_in,
                              void* d_out, int out_size, void* d_ws, size_t ws_size,
                              hipStream_t stream) {
  const float* x0   = (const float*)d_in[0];
  const float* Wx   = (const float*)d_in[1];
  const float* Wh   = (const float*)d_in[2];
  const float* Wops = (const float*)d_in[3];
  const float* emb  = (const float*)d_in[4];
  const float* u    = (const float*)d_in[5];
  (void)d_ws; (void)ws_size; (void)in_sizes; (void)n_in;

  setup_bpack<<<(NTIL*KTN*64 + 255)/256, 256, 0, stream>>>(Wh, Wops);
  setup_misc<<<(6*G4 + NCOL*4 + 255)/256, 256, 0, stream>>>(emb, Wx, Wh, Wops);
  setup_z0<<<BTOT/64, 256, 0, stream>>>(x0, Wx);
  rnn_main<<<NBLK, BLOCK, 0, stream>>>(u, (float*)d_out);
}

// Round 9
// 1873.154 us; speedup vs baseline: 1.1211x; 1.1211x over previous
//
#include <hip/hip_runtime.h>
#include <cstdint>
#include <cstddef>

typedef __attribute__((ext_vector_type(8))) short short8;   // 8 bf16 (4 VGPRs)
typedef __attribute__((ext_vector_type(4))) short bfx4;     // 4 bf16 (8 B)
typedef __attribute__((ext_vector_type(4))) float f32x4;

#define HH     100
#define G4     400
#define NTIL   26          // 400 gates + 5 logits + 11 pad = 26 tiles of 16
#define KTN    4           // 4 k-tiles of 32: k=0..99 real, 100..127 zero
#define BTOT   8192
#define TST    512
#define ROWS   32
#define NBLK   256
#define BLOCK  512          // 8 waves x 64; 2 waves/SIMD -> 256-reg budget/wave
#define ZW     420          // z_lds row stride (words)
#define EPW    404          // Ep2 row stride; 404%32=20 -> 6 ops hit 6 distinct banks
#define TANHC  1.5f
#define EPSF   1e-9f

__device__ unsigned short d_Bhi[NTIL*KTN*64*8];  // [W_h|W_ops|0] hi, B-frag order
__device__ unsigned short d_Blo[NTIL*KTN*64*8];  // lo residual
__device__ float d_Ep2[6*EPW];                   // emb @ W_x   [e][cell][gate]
__device__ float d_Z0[(size_t)BTOT*G4];          // x0 @ W_x    [b][n]

static __device__ __forceinline__ unsigned short bf16hi(float f){
  unsigned u = __float_as_uint(f);
  return (unsigned short)((u + 0x7FFFu + ((u>>16)&1u)) >> 16);   // RNE
}
static __device__ __forceinline__ float bf16f(unsigned short s){
  return __uint_as_float(((unsigned)s)<<16);
}
static __device__ __forceinline__ float frcp(float x){ return __builtin_amdgcn_rcpf(x); }
static __device__ __forceinline__ float sigf(float x){ return frcp(1.0f + __expf(-x)); }
static __device__ __forceinline__ float tanh_f(float x){ return 1.0f - 2.0f*frcp(__expf(2.0f*x) + 1.0f); }

// ---- setup kernels -------------------------------------------------------

// B-frag order for 16x16x32: n = tile*16 + (lane&15), k = kt*32 + (lane>>4)*8 + i
// KTN=4: k in 0..127, rows k>=100 are zero (covers old f32 residual rows 96-99)
__global__ void setup_bpack(const float* __restrict__ Wh, const float* __restrict__ Wops){
  int idx = blockIdx.x*blockDim.x + threadIdx.x;     // NTIL*KTN*64 = 6656
  if (idx >= NTIL*KTN*64) return;
  int tile = idx/(KTN*64), rem = idx - tile*(KTN*64), kt = rem>>6, ln = rem&63;
  int n = tile*16 + (ln & 15);
  #pragma unroll
  for (int i = 0; i < 8; ++i){
    int k = kt*32 + (ln>>4)*8 + i;
    float w = 0.f;
    if (k < HH){
      if (n < G4)          w = Wh[k*G4 + n];
      else if (n < G4+5)   w = Wops[k*5 + (n - G4)];
    }
    unsigned short hi = bf16hi(w);
    unsigned short lo = bf16hi(w - bf16f(hi));
    d_Bhi[idx*8+i] = hi;
    d_Blo[idx*8+i] = lo;
  }
}

__global__ void setup_misc(const float* __restrict__ emb, const float* __restrict__ Wx){
  int idx = blockIdx.x*blockDim.x + threadIdx.x;
  if (idx < 6*EPW){                                  // Ep2 [e][cell][gate], stride EPW
    int e = idx/EPW, r2 = idx - e*EPW, je = r2>>2, g = r2&3;
    float s = 0.f;
    if (je < HH)
      for (int k = 0; k < HH; ++k) s = fmaf(emb[e*HH+k], Wx[k*G4 + g*HH + je], s);
    d_Ep2[idx] = s;
  }
}

// Z0 = x0 @ W_x, stored [b][n]
__global__ __launch_bounds__(256) void setup_z0(const float* __restrict__ x0,
                                                const float* __restrict__ Wx){
  __shared__ float xs[64*101];
  const int bb = blockIdx.x * 64;                    // 128 blocks
  for (int i = threadIdx.x; i < 64*HH; i += 256){
    int r = i/HH, k = i - r*HH;
    xs[r*101 + k] = x0[(size_t)(bb + r)*HH + k];
  }
  __syncthreads();
  const int bl = threadIdx.x & 63;
  for (int ng = threadIdx.x >> 6; ng < HH; ng += 4){
    f32x4 a = {0.f,0.f,0.f,0.f};
    for (int k = 0; k < HH; ++k){
      f32x4 w = *(const f32x4*)&Wx[k*G4 + ng*4];
      a += w * xs[bl*101 + k];
    }
    *(f32x4*)&d_Z0[(size_t)(bb + bl)*G4 + ng*4] = a;
  }
}

// ---- main persistent kernel ---------------------------------------------
// r7 winner + residual MFMA-ification (KTN 3->4): the old f32 residual path
// (rows 96-99: h_res, Wres_l, 416 wave-fma, sampler dot-products, divergent
// pass-2) all becomes 3 extra MFMAs/tile on the 21%-utilized matrix pipe.
// A-frag rows k>=100 and B rows k>=100 are hard zero.
// Wave 0 computes the SWAPPED logits tile + samples FIRST, then its normal
// tiles -> the serial sampler chain overlaps other waves' MFMA streams.
// Tiles: w0 {23,24}+25sw; w1-5 {3(w-1)..+2}; w6 {15-18}; w7 {19-22}.

__global__ __launch_bounds__(BLOCK, 2) void rnn_main(
    const float* __restrict__ u, float* __restrict__ out)
{
  __shared__ __align__(16) float z_lds[ROWS*ZW];                // 53760 B
  __shared__ __align__(16) unsigned short fhi[2*KTN*64*8];      //  8192 B
  __shared__ __align__(16) unsigned short flo[2*KTN*64*8];      //  8192 B
  __shared__ __align__(16) float Ep2_l[6*EPW];                  //  9696 B
  __shared__ __align__(16) float gn_lds[ROWS*5];                //   640 B
  __shared__ int op_lds[ROWS];

  const int tid  = threadIdx.x;
  const int wave = tid >> 6;
  const int lane = tid & 63;
  const int cn   = lane & 15;       // col-in-tile (B,C) / row-in-tile (A)
  const int q4   = lane >> 4;       // quad
  const int row0 = blockIdx.x * ROWS;
  const int rE   = tid & 31;        // E row

  for (int i = tid; i < 6*EPW; i += BLOCK) Ep2_l[i] = d_Ep2[i];
  for (int i = tid; i < 2*KTN*64*8; i += BLOCK){ fhi[i] = 0; flo[i] = 0; }

  // persistent B-fragments (wave0: 23,24 normal + 25 swapped)
  const int tb  = (wave==0) ? 23 : (wave < 6) ? 3*(wave-1) : 15 + 4*(wave-6);
  const int ntl = (wave==0) ? 3 : (wave < 6) ? 3 : 4;  // tiles LOADED
  const int ngt = (wave==0) ? 2 : ntl;                 // tiles computed normally
  short8 bh[4][KTN], bl[4][KTN];
  {
    const short8* bph = (const short8*)d_Bhi;
    const short8* bpl = (const short8*)d_Blo;
    #pragma unroll
    for (int tl = 0; tl < 4; ++tl) if (tl < ntl)
      #pragma unroll
      for (int kt = 0; kt < KTN; ++kt){
        int fi = ((tb+tl)*KTN + kt)*64 + lane;
        bh[tl][kt] = bph[fi];
        bl[tl][kt] = bpl[fi];
      }
  }

  float cs1[4] = {0.f,0.f,0.f,0.f};   // pass-1 cells (jg 0..15)
  float cs2[4] = {0.f,0.f,0.f,0.f};   // pass-2 cells (jg 16..24)
  float lp_acc = 0.f, ent_acc = 0.f;

  for (int t = 0; t <= TST; ++t){
    // gumbel u prefetch (tid 416..447); HBM latency hides under G+E
    float upr[5];
    if (t < TST && tid >= 416 && tid < 448){
      const float* up = u + ((size_t)t*BTOT + row0 + (tid - 416))*5;
      #pragma unroll
      for (int o = 0; o < 5; ++o) upr[o] = up[o];
    }

    if (t == 0){
      // stage z_0 = x0 @ W_x (gates only)
      for (int i = tid; i < ROWS*HH; i += BLOCK){
        int r = i/HH, c4 = i - r*HH;
        *(f32x4*)&z_lds[r*ZW + c4*4] =
          *(const f32x4*)&d_Z0[(size_t)(row0 + r)*G4 + c4*4];
      }
    } else if (wave == 0){
      // ---- wave 0: swapped logits tile FIRST, sample, then tiles 23,24 ----
      f32x4 accT[2];
      #pragma unroll
      for (int mt = 0; mt < 2; ++mt){
        short8 ah[KTN], al[KTN];
        #pragma unroll
        for (int kt = 0; kt < KTN; ++kt){
          ah[kt] = *(const short8*)&fhi[((mt*KTN + kt)*64 + lane)*8];
          al[kt] = *(const short8*)&flo[((mt*KTN + kt)*64 + lane)*8];
        }
        f32x4 a = {0.f,0.f,0.f,0.f};
        #pragma unroll
        for (int kt = 0; kt < KTN; ++kt){             // term order mirrors normal
          a = __builtin_amdgcn_mfma_f32_16x16x32_bf16(bh[2][kt], ah[kt], a, 0,0,0);
          a = __builtin_amdgcn_mfma_f32_16x16x32_bf16(bh[2][kt], al[kt], a, 0,0,0);
          a = __builtin_amdgcn_mfma_f32_16x16x32_bf16(bl[2][kt], ah[kt], a, 0,0,0);
        }
        accT[mt] = a;
      }
      // rows 0-15: lane r has o0-3 in accT[0], o4 at lane r+16 reg 0
      float o4lo = __shfl_down(accT[0][0], 16);
      // rows 16-31: lane 16+r has o4 in its own accT[1][0]; o0-3 at lane r
      float t1o0 = __shfl_up(accT[1][0], 16);
      float t1o1 = __shfl_up(accT[1][1], 16);
      float t1o2 = __shfl_up(accT[1][2], 16);
      float t1o3 = __shfl_up(accT[1][3], 16);
      if (lane < 32){
        const int r = lane;
        float raw[5];
        if (lane < 16){
          raw[0] = accT[0][0]; raw[1] = accT[0][1];
          raw[2] = accT[0][2]; raw[3] = accT[0][3]; raw[4] = o4lo;
        } else {
          raw[0] = t1o0; raw[1] = t1o1; raw[2] = t1o2; raw[3] = t1o3;
          raw[4] = accT[1][0];
        }
        float l[5];
        #pragma unroll
        for (int o = 0; o < 5; ++o) l[o] = TANHC * tanh_f(raw[o]);
        int op = 0; float best = -1e30f;
        #pragma unroll
        for (int o = 0; o < 5; ++o){
          float v = l[o] + gn_lds[r*5 + o];
          if (v > best){ best = v; op = o; }            // strict >: first-max ties
        }
        float mx = fmaxf(fmaxf(fmaxf(l[0],l[1]), fmaxf(l[2],l[3])), l[4]);
        float se = 0.f;
        #pragma unroll
        for (int o = 0; o < 5; ++o) se += __expf(l[o] - mx);
        float lse = mx + __logf(se);
        float cur = lse - l[op];
        lp_acc  += cur;
        ent_acc += cur * __expf(-cur);
        op_lds[r] = op;
        out[2*BTOT + (size_t)(t-1)*BTOT + row0 + r] = (float)op;
      }
      // normal tiles 23,24 (after the sampler chain is off the critical path)
      #pragma unroll
      for (int mt = 0; mt < 2; ++mt){
        short8 ah[KTN], al[KTN];
        #pragma unroll
        for (int kt = 0; kt < KTN; ++kt){
          ah[kt] = *(const short8*)&fhi[((mt*KTN + kt)*64 + lane)*8];
          al[kt] = *(const short8*)&flo[((mt*KTN + kt)*64 + lane)*8];
        }
        #pragma unroll
        for (int tl = 0; tl < 2; ++tl){
          const int n = (23+tl)*16 + cn;
          f32x4 acc = {0.f,0.f,0.f,0.f};
          #pragma unroll
          for (int kt = 0; kt < KTN; ++kt){
            acc = __builtin_amdgcn_mfma_f32_16x16x32_bf16(ah[kt], bh[tl][kt], acc, 0,0,0);
            acc = __builtin_amdgcn_mfma_f32_16x16x32_bf16(al[kt], bh[tl][kt], acc, 0,0,0);
            acc = __builtin_amdgcn_mfma_f32_16x16x32_bf16(ah[kt], bl[tl][kt], acc, 0,0,0);
          }
          const int rowb = mt*16 + q4*4;                // C: row=q4*4+reg, col=cn
          #pragma unroll
          for (int i = 0; i < 4; ++i)
            z_lds[(rowb + i)*ZW + n] = acc[i];
        }
      }
    } else {
      // ---- waves 1-7: normal gate tiles, full K via MFMA ----
      #pragma unroll
      for (int mt = 0; mt < 2; ++mt){
        short8 ah[KTN], al[KTN];
        #pragma unroll
        for (int kt = 0; kt < KTN; ++kt){
          ah[kt] = *(const short8*)&fhi[((mt*KTN + kt)*64 + lane)*8];
          al[kt] = *(const short8*)&flo[((mt*KTN + kt)*64 + lane)*8];
        }
        #pragma unroll
        for (int tl = 0; tl < 4; ++tl) if (tl < ngt){
          const int n = (tb+tl)*16 + cn;
          f32x4 acc = {0.f,0.f,0.f,0.f};
          #pragma unroll
          for (int kt = 0; kt < KTN; ++kt){
            acc = __builtin_amdgcn_mfma_f32_16x16x32_bf16(ah[kt], bh[tl][kt], acc, 0,0,0);
            acc = __builtin_amdgcn_mfma_f32_16x16x32_bf16(al[kt], bh[tl][kt], acc, 0,0,0);
            acc = __builtin_amdgcn_mfma_f32_16x16x32_bf16(ah[kt], bl[tl][kt], acc, 0,0,0);
          }
          const int rowb = mt*16 + q4*4;                // C: row=q4*4+reg, col=cn
          #pragma unroll
          for (int i = 0; i < 4; ++i)
            z_lds[(rowb + i)*ZW + n] = acc[i];
        }
      }
    }
    if (t == TST) break;
    __syncthreads();   // b1: z_t + op_{t-1} ready

    // ---- E: LSTM elementwise, uniform frag path (no residual special case) ----
    const int opv = (t > 0) ? op_lds[rE] : 0;
    // pass 1: all 512 threads, jg = tid>>5 in 0..15 (cells 0..63)
    {
      const int jg = tid >> 5;
      f32x4 zg[4];
      #pragma unroll
      for (int g = 0; g < 4; ++g)
        zg[g] = *(const f32x4*)&z_lds[rE*ZW + g*HH + jg*4];
      if (t > 0){
        #pragma unroll
        for (int i = 0; i < 4; ++i){
          f32x4 e4 = *(const f32x4*)&Ep2_l[opv*EPW + (jg*4 + i)*4];
          zg[0][i] += e4.x; zg[1][i] += e4.y; zg[2][i] += e4.z; zg[3][i] += e4.w;
        }
      }
      float hv[4];
      #pragma unroll
      for (int i = 0; i < 4; ++i){
        float cn_ = sigf(zg[1][i])*cs1[i] + sigf(zg[0][i])*tanh_f(zg[2][i]);
        cs1[i] = cn_;
        hv[i] = sigf(zg[3][i])*tanh_f(cn_);
      }
      bfx4 h4, l4;
      #pragma unroll
      for (int i = 0; i < 4; ++i){
        unsigned short hi = bf16hi(hv[i]);
        h4[i] = (short)hi;
        l4[i] = (short)bf16hi(hv[i] - bf16f(hi));
      }
      const int kt   = jg >> 3;
      const int lf   = (rE & 15) | (((jg >> 1) & 3) << 4);
      const int mt   = rE >> 4;
      const int j0   = (jg & 1) * 4;
      const int base = ((mt*KTN + kt)*64 + lf)*8 + j0;
      *(bfx4*)&fhi[base] = h4;
      *(bfx4*)&flo[base] = l4;
    }
    // pass 2: tid<288 -> jg 16..24 (uniform frag write; jg24 lands in kt=3);
    // tid 416..447 -> gumbel noise
    if (tid < 288){
      const int jg = 16 + (tid >> 5);
      f32x4 zg[4];
      #pragma unroll
      for (int g = 0; g < 4; ++g)
        zg[g] = *(const f32x4*)&z_lds[rE*ZW + g*HH + jg*4];
      if (t > 0){
        #pragma unroll
        for (int i = 0; i < 4; ++i){
          f32x4 e4 = *(const f32x4*)&Ep2_l[opv*EPW + (jg*4 + i)*4];
          zg[0][i] += e4.x; zg[1][i] += e4.y; zg[2][i] += e4.z; zg[3][i] += e4.w;
        }
      }
      float hv[4];
      #pragma unroll
      for (int i = 0; i < 4; ++i){
        float cn_ = sigf(zg[1][i])*cs2[i] + sigf(zg[0][i])*tanh_f(zg[2][i]);
        cs2[i] = cn_;
        hv[i] = sigf(zg[3][i])*tanh_f(cn_);
      }
      bfx4 h4, l4;
      #pragma unroll
      for (int i = 0; i < 4; ++i){
        unsigned short hi = bf16hi(hv[i]);
        h4[i] = (short)hi;
        l4[i] = (short)bf16hi(hv[i] - bf16f(hi));
      }
      const int kt   = jg >> 3;                        // 2 (jg 16-23) or 3 (jg 24)
      const int lf   = (rE & 15) | (((jg >> 1) & 3) << 4);
      const int mt   = rE >> 4;
      const int j0   = (jg & 1) * 4;
      const int base = ((mt*KTN + kt)*64 + lf)*8 + j0;
      *(bfx4*)&fhi[base] = h4;
      *(bfx4*)&flo[base] = l4;
    } else if (tid >= 416 && tid < 448){
      // gumbel noise for u[t] (consumed at G_{t+1}); loads issued at loop top
      int r = tid - 416;
      #pragma unroll
      for (int o = 0; o < 5; ++o)
        gn_lds[r*5 + o] = -__logf(-__logf(upr[o] + EPSF) + EPSF);
    }
    __syncthreads();   // b2: h_{t+1} frags + gn ready
  }

  if (wave == 0 && lane < 32){
    out[row0 + lane]        = lp_acc;
    out[BTOT + row0 + lane] = ent_acc;
  }
}

extern "C" void kernel_launch(void* const* d_in, const int* in_sizes, int n_in,
                              void* d_out, int out_size, void* d_ws, size_t ws_size,
                              hipStream_t stream) {
  const float* x0   = (const float*)d_in[0];
  const float* Wx   = (const float*)d_in[1];
  const float* Wh   = (const float*)d_in[2];
  const float* Wops = (const float*)d_in[3];
  const float* emb  = (const float*)d_in[4];
  const float* u    = (const float*)d_in[5];
  (void)d_ws; (void)ws_size; (void)in_sizes; (void)n_in;

  setup_bpack<<<(NTIL*KTN*64 + 255)/256, 256, 0, stream>>>(Wh, Wops);
  setup_misc<<<(6*EPW + 255)/256, 256, 0, stream>>>(emb, Wx);
  setup_z0<<<BTOT/64, 256, 0, stream>>>(x0, Wx);
  rnn_main<<<NBLK, BLOCK, 0, stream>>>(u, (float*)d_out);
}